// Round 10
// baseline (267.325 us; speedup 1.0000x reference)
//
#include <hip/hip_runtime.h>
#include <math.h>

#define NFEAT 128
#define EPSBN 1e-5f
#define LDA 136   // bf16 elems per LDS row: 128 + 8 pad
#define NREP 8    // logit3 replicas to spread atomic contention

typedef __attribute__((ext_vector_type(8))) short short8;
typedef __attribute__((ext_vector_type(4))) float f32x4;

__device__ __forceinline__ unsigned short f2bf(float x) {
  union { float f; unsigned u; } v; v.f = x;
  unsigned r = v.u + 0x7FFF + ((v.u >> 16) & 1);   // RNE
  return (unsigned short)(r >> 16);
}
__device__ __forceinline__ float bf2f(unsigned short h) {
  union { unsigned u; float f; } v; v.u = (unsigned)h << 16;
  return v.f;
}

// ---------------------------------------------------------------------------
// KP: blocks 0..23: split W' = (W + I) into bf16 hi/lo planes in MFMA
// B-fragment order (for the stats pass).  Blocks 24..29: fold back-half into
// MT + cb.  logits = S@M1 + I@M3 + R@M4 + NB@M2 + cb.
// MT layout: MT[cl*512 + part*128 + k], part: 0=S 1=I 2=R 3=NB.
// ---------------------------------------------------------------------------
__global__ __launch_bounds__(256) void kp_params(
    const float* __restrict__ Ws, const float* __restrict__ Wi,
    const float* __restrict__ Wr,
    const float* __restrict__ WtoI, const float* __restrict__ btoI,
    const float* __restrict__ WtoR, const float* __restrict__ btoR,
    const float* __restrict__ Wout, const float* __restrict__ bout,
    short* __restrict__ Whi, short* __restrict__ Wlo,
    float* __restrict__ MT, float* __restrict__ cb)
{
  const int tid = threadIdx.x;
  if (blockIdx.x < 24) {
    int t = blockIdx.x * 256 + tid;   // 6144 total
    int m   = t >> 11;
    int rem = t & 2047;
    int kf  = rem >> 9;
    int kg  = (rem >> 7) & 3;
    int c   = rem & 127;
    const float* W = (m == 0) ? Ws : ((m == 1) ? Wi : Wr);
    short hb[8], lb[8];
#pragma unroll
    for (int j = 0; j < 8; j++) {
      int k = kf * 32 + kg * 8 + j;
      float w = W[(size_t)k * NFEAT + c] + (k == c ? 1.0f : 0.0f);
      unsigned short h = f2bf(w);
      hb[j] = (short)h;
      lb[j] = (short)f2bf(w - bf2f(h));
    }
    int base = ((m * 16 + kf * 4 + kg) << 10) + (c << 3);
    *(short8*)&Whi[base] = *(short8*)hb;
    *(short8*)&Wlo[base] = *(short8*)lb;
    return;
  }

  int t = (blockIdx.x - 24) * 256 + tid;   // 0..1535
  int cl = t / 512;
  int idx = t - cl * 512;
  int part = idx >> 7, k = idx & 127;
  float val;
  if (part == 0) {            // S: Wo1 + WtoI_top @ (Wo2-Wo1)
    float s = Wout[k * 3 + cl];
    for (int f = 0; f < 128; f++)
      s = fmaf(WtoI[k * 128 + f],
               Wout[(128 + f) * 3 + cl] - Wout[f * 3 + cl], s);
    val = s;
  } else if (part == 1) {     // I: Wo2 + WtoR @ (Wo3-Wo2)
    float s = Wout[(128 + k) * 3 + cl];
    for (int f = 0; f < 128; f++)
      s = fmaf(WtoR[k * 128 + f],
               Wout[(256 + f) * 3 + cl] - Wout[(128 + f) * 3 + cl], s);
    val = s;
  } else if (part == 2) {     // R: Wo3
    val = Wout[(256 + k) * 3 + cl];
  } else {                    // NB: WtoI_bot @ (Wo2-Wo1)
    float s = 0.f;
    for (int f = 0; f < 128; f++)
      s = fmaf(WtoI[(128 + k) * 128 + f],
               Wout[(128 + f) * 3 + cl] - Wout[f * 3 + cl], s);
    val = s;
  }
  MT[cl * 512 + idx] = val;

  if (blockIdx.x == 24 && tid < 3) {
    float s = bout[tid];
    for (int f = 0; f < 128; f++) {
      s = fmaf(btoI[f], Wout[(128 + f) * 3 + tid] - Wout[f * 3 + tid], s);
      s = fmaf(btoR[f], Wout[(256 + f) * 3 + tid] - Wout[(128 + f) * 3 + tid], s);
    }
    cb[tid] = s;
  }
}

// ---------------------------------------------------------------------------
// K1a (stats-only GEMM): column sum/sumsq of P_w = feat @ (W_w+I) + b_w.
// Same proven structure as before, with P stores and residual reads deleted.
// ---------------------------------------------------------------------------
__global__ __launch_bounds__(512, 2) void k1a_stats(
    const float* __restrict__ feat,
    const short* __restrict__ Whi, const short* __restrict__ Wlo,
    const float* __restrict__ bs, const float* __restrict__ bi,
    const float* __restrict__ br,
    float* __restrict__ stats,   // 6*128
    int N, int ntiles)
{
  __shared__ short Ah[2][64 * LDA];
  __shared__ short Al[2][64 * LDA];

  const int tid  = threadIdx.x;
  const int lane = tid & 63;
  const int wv   = tid >> 6;
  const int colb = wv * 16 + (lane & 15);
  const int kg   = lane >> 4;
  const int krow = kg * 8;

  const int sr = tid >> 3;
  const int so = tid & 7;

  const float bias[3] = {bs[colb], bi[colb], br[colb]};
  float ssum[3] = {0.f, 0.f, 0.f}, ssq[3] = {0.f, 0.f, 0.f};

  float4 pf[4];
  {
    int gr = blockIdx.x * 64 + sr; if (gr >= N) gr = N - 1;
    const float4* s4 = (const float4*)(feat + (size_t)gr * NFEAT + so * 16);
#pragma unroll
    for (int q = 0; q < 4; q++) pf[q] = s4[q];
    short hbuf[16], lbuf[16];
#pragma unroll
    for (int q = 0; q < 4; q++) {
      float xs[4] = {pf[q].x, pf[q].y, pf[q].z, pf[q].w};
#pragma unroll
      for (int cc = 0; cc < 4; cc++) {
        unsigned short h = f2bf(xs[cc]);
        hbuf[q * 4 + cc] = (short)h;
        lbuf[q * 4 + cc] = (short)f2bf(xs[cc] - bf2f(h));
      }
    }
    *(short8*)&Ah[0][sr * LDA + so * 16]     = *(short8*)(hbuf);
    *(short8*)&Ah[0][sr * LDA + so * 16 + 8] = *(short8*)(hbuf + 8);
    *(short8*)&Al[0][sr * LDA + so * 16]     = *(short8*)(lbuf);
    *(short8*)&Al[0][sr * LDA + so * 16 + 8] = *(short8*)(lbuf + 8);
  }
  __syncthreads();

  int cur = 0;
  for (int tile = blockIdx.x; tile < ntiles; tile += gridDim.x) {
    const int row0 = tile * 64;
    const int ntile = tile + gridDim.x;
    const bool have_next = ntile < ntiles;

    if (have_next) {
      int gr = ntile * 64 + sr; if (gr >= N) gr = N - 1;
      const float4* s4 = (const float4*)(feat + (size_t)gr * NFEAT + so * 16);
#pragma unroll
      for (int q = 0; q < 4; q++) pf[q] = s4[q];
    }

    const short* ah_c = &Ah[cur][0];
    const short* al_c = &Al[cur][0];

    f32x4 acc[3][4];
#pragma unroll
    for (int m = 0; m < 3; m++)
#pragma unroll
      for (int rf = 0; rf < 4; rf++)
        acc[m][rf] = (f32x4){0.f, 0.f, 0.f, 0.f};

#pragma unroll
    for (int kf = 0; kf < 4; kf++) {
      short8 bh[3], bl[3];
#pragma unroll
      for (int m = 0; m < 3; m++) {
        int fb = ((m * 16 + kf * 4 + kg) << 10) + (colb << 3);
        bh[m] = *(const short8*)&Whi[fb];
        bl[m] = *(const short8*)&Wlo[fb];
      }
      short8 ah[4], al[4];
#pragma unroll
      for (int rf = 0; rf < 4; rf++) {
        int off = (rf * 16 + (lane & 15)) * LDA + kf * 32 + krow;
        ah[rf] = *(const short8*)&ah_c[off];
        al[rf] = *(const short8*)&al_c[off];
      }
#pragma unroll
      for (int m = 0; m < 3; m++) {
#pragma unroll
        for (int rf = 0; rf < 4; rf++) {
          acc[m][rf] = __builtin_amdgcn_mfma_f32_16x16x32_bf16(
              ah[rf], bh[m], acc[m][rf], 0, 0, 0);
          acc[m][rf] = __builtin_amdgcn_mfma_f32_16x16x32_bf16(
              al[rf], bh[m], acc[m][rf], 0, 0, 0);
          acc[m][rf] = __builtin_amdgcn_mfma_f32_16x16x32_bf16(
              ah[rf], bl[m], acc[m][rf], 0, 0, 0);
        }
      }
    }

    // stats only (residual already in W' via +I)
#pragma unroll
    for (int rf = 0; rf < 4; rf++) {
      int lrb = rf * 16 + kg * 4;
#pragma unroll
      for (int g = 0; g < 4; g++) {
        bool ok = (row0 + lrb + g) < N;
#pragma unroll
        for (int m = 0; m < 3; m++) {
          float v = acc[m][rf][g] + bias[m];
          if (ok) { ssum[m] += v; ssq[m] += v * v; }
        }
      }
    }

    if (have_next) {
      short hbuf[16], lbuf[16];
#pragma unroll
      for (int q = 0; q < 4; q++) {
        float xs[4] = {pf[q].x, pf[q].y, pf[q].z, pf[q].w};
#pragma unroll
        for (int cc = 0; cc < 4; cc++) {
          unsigned short h = f2bf(xs[cc]);
          hbuf[q * 4 + cc] = (short)h;
          lbuf[q * 4 + cc] = (short)f2bf(xs[cc] - bf2f(h));
        }
      }
      int nb = cur ^ 1;
      *(short8*)&Ah[nb][sr * LDA + so * 16]     = *(short8*)(hbuf);
      *(short8*)&Ah[nb][sr * LDA + so * 16 + 8] = *(short8*)(hbuf + 8);
      *(short8*)&Al[nb][sr * LDA + so * 16]     = *(short8*)(lbuf);
      *(short8*)&Al[nb][sr * LDA + so * 16 + 8] = *(short8*)(lbuf + 8);
    }
    __syncthreads();
    cur ^= 1;
  }

#pragma unroll
  for (int m = 0; m < 3; m++) {
    float s = ssum[m], q = ssq[m];
    s += __shfl_xor(s, 16); s += __shfl_xor(s, 32);
    q += __shfl_xor(q, 16); q += __shfl_xor(q, 32);
    if (kg == 0) {
      unsafeAtomicAdd(&stats[m * 256 + colb], s);
      unsafeAtomicAdd(&stats[m * 256 + 128 + colb], q);
    }
  }
}

// ---------------------------------------------------------------------------
// K_bnscale: blocks 0..23: W'' = (W+I)·diag(a_m) split-bf16 (fragment order).
// Block 24: kvec[m][c] = a·(bias_m[c] − μ) + β.  a = γ·rsqrt(var+ε).
// ---------------------------------------------------------------------------
__global__ __launch_bounds__(256) void k_bnscale(
    const float* __restrict__ Ws, const float* __restrict__ Wi,
    const float* __restrict__ Wr,
    const float* __restrict__ bs, const float* __restrict__ bi,
    const float* __restrict__ br,
    const float* __restrict__ gamma, const float* __restrict__ beta,
    const float* __restrict__ stats,
    short* __restrict__ Whi2, short* __restrict__ Wlo2,
    float* __restrict__ kvec, float invN)
{
  const int tid = threadIdx.x;
  if (blockIdx.x < 24) {
    int t = blockIdx.x * 256 + tid;
    int m   = t >> 11;
    int rem = t & 2047;
    int kf  = rem >> 9;
    int kg  = (rem >> 7) & 3;
    int c   = rem & 127;
    const float* W = (m == 0) ? Ws : ((m == 1) ? Wi : Wr);
    float mu = stats[m * 256 + c] * invN;
    float var = stats[m * 256 + 128 + c] * invN - mu * mu;
    float a = gamma[c] * rsqrtf(var + EPSBN);
    short hb[8], lb[8];
#pragma unroll
    for (int j = 0; j < 8; j++) {
      int k = kf * 32 + kg * 8 + j;
      float w = (W[(size_t)k * NFEAT + c] + (k == c ? 1.0f : 0.0f)) * a;
      unsigned short h = f2bf(w);
      hb[j] = (short)h;
      lb[j] = (short)f2bf(w - bf2f(h));
    }
    int base = ((m * 16 + kf * 4 + kg) << 10) + (c << 3);
    *(short8*)&Whi2[base] = *(short8*)hb;
    *(short8*)&Wlo2[base] = *(short8*)lb;
    return;
  }
  // kvec
  if (tid < 384) {
    int m = tid >> 7, c = tid & 127;
    const float* B = (m == 0) ? bs : ((m == 1) ? bi : br);
    float mu = stats[m * 256 + c] * invN;
    float var = stats[m * 256 + 128 + c] * invN - mu * mu;
    float a = gamma[c] * rsqrtf(var + EPSBN);
    kvec[m * 128 + c] = a * (B[c] - mu) + beta[c];
  }
}

// ---------------------------------------------------------------------------
// K1f: fused main pass, no LDS, no barriers.  Wave owns 32 rows x 128 cols.
// acc = feat @ W''_m (BN scale baked in); v = relu(acc + kvec);
// slog[r][cl] = sum_m sum_c v_m MT[cl][m*128+c];  q[r][cl] = sum_c v_i MTq.
// Also zeroes logit3R for this block's rows.
// ---------------------------------------------------------------------------
__global__ __launch_bounds__(512, 2) void k1f_fused(
    const float* __restrict__ feat,
    const short* __restrict__ Whi2, const short* __restrict__ Wlo2,
    const float* __restrict__ MT, const float* __restrict__ kvec,
    float* __restrict__ slogA, float* __restrict__ qv,
    float* __restrict__ logit3R, int N, int N4)
{
  const int tid  = threadIdx.x;
  const int lane = tid & 63;
  const int wv   = tid >> 6;
  const int kg   = lane >> 4;
  const int l15  = lane & 15;

  // zero logit3R for this block's 256 rows x NREP reps
  {
    int base_r = blockIdx.x * 256;
#pragma unroll
    for (int i = 0; i < 4; i++) {
      int idx = i * 512 + tid;          // 2048 float4 slots
      int rep = idx >> 8;
      int ro  = idx & 255;
      int r = base_r + ro;
      if (r < N)
        *(float4*)&logit3R[(size_t)rep * N4 + (size_t)r * 4] =
            make_float4(0.f, 0.f, 0.f, 0.f);
    }
  }

  const int rowbase = blockIdx.x * 256 + wv * 32;

  // ---- A fragments (32 rows, split-bf16) in registers
  short8 ah[2][4], al[2][4];
#pragma unroll
  for (int rf = 0; rf < 2; rf++) {
    int r = rowbase + rf * 16 + l15; if (r >= N) r = N - 1;
    const float4* fp = (const float4*)(feat + (size_t)r * NFEAT);
#pragma unroll
    for (int kf = 0; kf < 4; kf++) {
      float4 x0 = fp[kf * 8 + kg * 2];
      float4 x1 = fp[kf * 8 + kg * 2 + 1];
      float xs[8] = {x0.x, x0.y, x0.z, x0.w, x1.x, x1.y, x1.z, x1.w};
      short hb[8], lb[8];
#pragma unroll
      for (int j = 0; j < 8; j++) {
        unsigned short h = f2bf(xs[j]);
        hb[j] = (short)h;
        lb[j] = (short)f2bf(xs[j] - bf2f(h));
      }
      ah[rf][kf] = *(short8*)hb;
      al[rf][kf] = *(short8*)lb;
    }
  }

  float sac[2][4][3];   // slog partials per (rf, g, cl)
  float qac[2][4][3];   // q partials
#pragma unroll
  for (int rf = 0; rf < 2; rf++)
#pragma unroll
    for (int g = 0; g < 4; g++)
#pragma unroll
      for (int cl = 0; cl < 3; cl++) { sac[rf][g][cl] = 0.f; qac[rf][g][cl] = 0.f; }

#pragma unroll
  for (int m = 0; m < 3; m++) {
    f32x4 acc[8][2];
#pragma unroll
    for (int cg = 0; cg < 8; cg++)
#pragma unroll
      for (int rf = 0; rf < 2; rf++)
        acc[cg][rf] = (f32x4){0.f, 0.f, 0.f, 0.f};

#pragma unroll
    for (int kf = 0; kf < 4; kf++) {
#pragma unroll
      for (int cg = 0; cg < 8; cg++) {
        int fb = ((m * 16 + kf * 4 + kg) << 10) + ((cg * 16 + l15) << 3);
        short8 bh = *(const short8*)&Whi2[fb];
        short8 bl = *(const short8*)&Wlo2[fb];
#pragma unroll
        for (int rf = 0; rf < 2; rf++) {
          acc[cg][rf] = __builtin_amdgcn_mfma_f32_16x16x32_bf16(
              ah[rf][kf], bh, acc[cg][rf], 0, 0, 0);
          acc[cg][rf] = __builtin_amdgcn_mfma_f32_16x16x32_bf16(
              al[rf][kf], bh, acc[cg][rf], 0, 0, 0);
          acc[cg][rf] = __builtin_amdgcn_mfma_f32_16x16x32_bf16(
              ah[rf][kf], bl, acc[cg][rf], 0, 0, 0);
        }
      }
    }

    // epilogue for this m: v = relu(acc + kvec), dot with MT columns
    float kc[8], mt0[8], mt1[8], mt2[8];
#pragma unroll
    for (int cg = 0; cg < 8; cg++) {
      int c = cg * 16 + l15;
      kc[cg]  = kvec[m * 128 + c];
      mt0[cg] = MT[0 * 512 + m * 128 + c];
      mt1[cg] = MT[1 * 512 + m * 128 + c];
      mt2[cg] = MT[2 * 512 + m * 128 + c];
    }
    if (m == 1) {
      float mq0[8], mq1[8], mq2[8];
#pragma unroll
      for (int cg = 0; cg < 8; cg++) {
        int c = cg * 16 + l15;
        mq0[cg] = MT[0 * 512 + 384 + c];
        mq1[cg] = MT[1 * 512 + 384 + c];
        mq2[cg] = MT[2 * 512 + 384 + c];
      }
#pragma unroll
      for (int rf = 0; rf < 2; rf++)
#pragma unroll
        for (int g = 0; g < 4; g++)
#pragma unroll
          for (int cg = 0; cg < 8; cg++) {
            float v = fmaxf(acc[cg][rf][g] + kc[cg], 0.f);
            sac[rf][g][0] = fmaf(v, mt0[cg], sac[rf][g][0]);
            sac[rf][g][1] = fmaf(v, mt1[cg], sac[rf][g][1]);
            sac[rf][g][2] = fmaf(v, mt2[cg], sac[rf][g][2]);
            qac[rf][g][0] = fmaf(v, mq0[cg], qac[rf][g][0]);
            qac[rf][g][1] = fmaf(v, mq1[cg], qac[rf][g][1]);
            qac[rf][g][2] = fmaf(v, mq2[cg], qac[rf][g][2]);
          }
    } else {
#pragma unroll
      for (int rf = 0; rf < 2; rf++)
#pragma unroll
        for (int g = 0; g < 4; g++)
#pragma unroll
          for (int cg = 0; cg < 8; cg++) {
            float v = fmaxf(acc[cg][rf][g] + kc[cg], 0.f);
            sac[rf][g][0] = fmaf(v, mt0[cg], sac[rf][g][0]);
            sac[rf][g][1] = fmaf(v, mt1[cg], sac[rf][g][1]);
            sac[rf][g][2] = fmaf(v, mt2[cg], sac[rf][g][2]);
          }
    }
  }

  // ---- reduce over 16 lanes (cols) and write slog / q
#pragma unroll
  for (int rf = 0; rf < 2; rf++)
#pragma unroll
    for (int g = 0; g < 4; g++) {
      float s0 = sac[rf][g][0], s1 = sac[rf][g][1], s2 = sac[rf][g][2];
      float q0 = qac[rf][g][0], q1 = qac[rf][g][1], q2 = qac[rf][g][2];
#pragma unroll
      for (int off = 1; off < 16; off <<= 1) {
        s0 += __shfl_xor(s0, off); s1 += __shfl_xor(s1, off);
        s2 += __shfl_xor(s2, off);
        q0 += __shfl_xor(q0, off); q1 += __shfl_xor(q1, off);
        q2 += __shfl_xor(q2, off);
      }
      if (l15 == 0) {
        int r = rowbase + rf * 16 + kg * 4 + g;
        if (r < N) {
          *(float4*)&slogA[(size_t)r * 4] = make_float4(s0, s1, s2, 0.f);
          *(float4*)&qv[(size_t)r * 4]    = make_float4(q0, q1, q2, 0.f);
        }
      }
    }
}

// ---------------------------------------------------------------------------
// K_edge: 64 lanes = 21 edges x 3 comps; one atomic/lane, same-line merge,
// replica (waveID&7) spreads contention.
// ---------------------------------------------------------------------------
__global__ __launch_bounds__(256) void k_edge(
    const int* __restrict__ eidx, const float* __restrict__ ew,
    const float* __restrict__ q, float* __restrict__ logit3R,
    int E, int N4)
{
  const int wid  = (blockIdx.x * 256 + threadIdx.x) >> 6;
  const int lane = threadIdx.x & 63;
  const int el   = lane / 3;
  const int comp = lane - el * 3;
  if (el >= 21) return;
  const int e = wid * 21 + el;
  if (e >= E) return;

  int src = eidx[e];
  int dst = eidx[E + e];
  float w = ew[e];
  float qvv = q[(size_t)src * 4 + comp];
  int rep = wid & (NREP - 1);
  unsafeAtomicAdd(&logit3R[(size_t)rep * N4 + (size_t)dst * 4 + comp], qvv * w);
}

// ---------------------------------------------------------------------------
// K4t: out[r] = softmax(slog[r] + sum_rep logit3R[rep][r] + cb).
// ---------------------------------------------------------------------------
__global__ __launch_bounds__(256) void k4_final(
    const float* __restrict__ slogA, const float* __restrict__ logit3R,
    const float* __restrict__ cb,
    float* __restrict__ out, int N, int N4)
{
  int r = blockIdx.x * 256 + threadIdx.x;
  if (r >= N) return;
  float4 S = *(const float4*)&slogA[(size_t)r * 4];
  float l0 = S.x + cb[0], l1 = S.y + cb[1], l2 = S.z + cb[2];
#pragma unroll
  for (int rep = 0; rep < NREP; rep++) {
    float4 L = *(const float4*)&logit3R[(size_t)rep * N4 + (size_t)r * 4];
    l0 += L.x; l1 += L.y; l2 += L.z;
  }
  float mx = fmaxf(l0, fmaxf(l1, l2));
  float e0 = expf(l0 - mx), e1 = expf(l1 - mx), e2 = expf(l2 - mx);
  float inv = 1.f / (e0 + e1 + e2);
  out[(size_t)r * 3 + 0] = e0 * inv;
  out[(size_t)r * 3 + 1] = e1 * inv;
  out[(size_t)r * 3 + 2] = e2 * inv;
}

// ---------------------------------------------------------------------------
extern "C" void kernel_launch(void* const* d_in, const int* in_sizes, int n_in,
                              void* d_out, int out_size, void* d_ws, size_t ws_size,
                              hipStream_t stream)
{
  const float* feat  = (const float*)d_in[0];
  const int*   eidx  = (const int*)  d_in[1];
  const float* ew    = (const float*)d_in[2];
  const float* Ws    = (const float*)d_in[3];
  const float* bs    = (const float*)d_in[4];
  const float* Wi    = (const float*)d_in[5];
  const float* bi    = (const float*)d_in[6];
  const float* Wr    = (const float*)d_in[7];
  const float* br    = (const float*)d_in[8];
  const float* gamma = (const float*)d_in[9];
  const float* beta  = (const float*)d_in[10];
  const float* WtoI  = (const float*)d_in[11];
  const float* btoI  = (const float*)d_in[12];
  const float* WtoR  = (const float*)d_in[13];
  const float* btoR  = (const float*)d_in[14];
  const float* Wout  = (const float*)d_in[15];
  const float* bout  = (const float*)d_in[16];

  const int N = in_sizes[0] / NFEAT;
  const int E = in_sizes[2];
  const int N4 = 4 * N;
  const float invN = 1.0f / (float)N;
  float* out = (float*)d_out;

  float* logit3R = (float*)d_ws;                 // NREP*4*N
  float* slogA   = logit3R + (size_t)NREP * N4;  // 4*N
  float* qv      = slogA + 4 * (size_t)N;        // 4*N
  float* stats   = qv + 4 * (size_t)N;           // 768
  float* MT      = stats + 768;                  // 1536
  float* cb      = MT + 1536;                    // 4
  float* kvec    = cb + 4;                       // 384
  short* Whi     = (short*)(kvec + 384);         // 49152
  short* Wlo     = Whi + 49152;                  // 49152
  short* Whi2    = Wlo + 49152;                  // 49152
  short* Wlo2    = Whi2 + 49152;                 // 49152

  hipMemsetAsync(stats, 0, 768 * sizeof(float), stream);

  const int nt = (N + 63) / 64;           // 1563
  const int g1 = (nt + 2) / 3;            // 521

  kp_params<<<30, 256, 0, stream>>>(Ws, Wi, Wr, WtoI, btoI, WtoR, btoR,
                                    Wout, bout, Whi, Wlo, MT, cb);
  k1a_stats<<<g1, 512, 0, stream>>>(feat, Whi, Wlo, bs, bi, br, stats, N, nt);
  k_bnscale<<<25, 256, 0, stream>>>(Ws, Wi, Wr, bs, bi, br, gamma, beta,
                                    stats, Whi2, Wlo2, kvec, invN);
  const int gf = (N + 255) / 256;         // 391
  k1f_fused<<<gf, 512, 0, stream>>>(feat, Whi2, Wlo2, MT, kvec,
                                    slogA, qv, logit3R, N, N4);
  const int nwaves = (E + 20) / 21;
  k_edge<<<(nwaves + 3) / 4, 256, 0, stream>>>(eidx, ew, qv, logit3R, E, N4);
  k4_final<<<gf, 256, 0, stream>>>(slogA, logit3R, cb, out, N, N4);
}

// Round 11
// 219.273 us; speedup vs baseline: 1.2191x; 1.2191x over previous
//
#include <hip/hip_runtime.h>
#include <math.h>

#define NFEAT 128
#define EPSBN 1e-5f
#define LDA 136   // bf16 elems per LDS row: 128 + 8 pad
#define NREP 8    // logit3 replicas to spread atomic contention

typedef __attribute__((ext_vector_type(8))) short short8;
typedef __attribute__((ext_vector_type(4))) float f32x4;

__device__ __forceinline__ unsigned short f2bf(float x) {
  union { float f; unsigned u; } v; v.f = x;
  unsigned r = v.u + 0x7FFF + ((v.u >> 16) & 1);   // RNE
  return (unsigned short)(r >> 16);
}
__device__ __forceinline__ float bf2f(unsigned short h) {
  union { unsigned u; float f; } v; v.u = (unsigned)h << 16;
  return v.f;
}

// ---------------------------------------------------------------------------
// KP: blocks 0..23: split W' = (W + I) into bf16 hi/lo planes in MFMA
// B-fragment order (for the stats pass).  Blocks 24..29: fold back-half into
// MT + cb.  logits = S@M1 + I@M3 + R@M4 + NB@M2 + cb.
// MT layout: MT[cl*512 + part*128 + k], part: 0=S 1=I 2=R 3=NB.
// ---------------------------------------------------------------------------
__global__ __launch_bounds__(256) void kp_params(
    const float* __restrict__ Ws, const float* __restrict__ Wi,
    const float* __restrict__ Wr,
    const float* __restrict__ WtoI, const float* __restrict__ btoI,
    const float* __restrict__ WtoR, const float* __restrict__ btoR,
    const float* __restrict__ Wout, const float* __restrict__ bout,
    short* __restrict__ Whi, short* __restrict__ Wlo,
    float* __restrict__ MT, float* __restrict__ cb)
{
  const int tid = threadIdx.x;
  if (blockIdx.x < 24) {
    int t = blockIdx.x * 256 + tid;   // 6144 total
    int m   = t >> 11;
    int rem = t & 2047;
    int kf  = rem >> 9;
    int kg  = (rem >> 7) & 3;
    int c   = rem & 127;
    const float* W = (m == 0) ? Ws : ((m == 1) ? Wi : Wr);
    short hb[8], lb[8];
#pragma unroll
    for (int j = 0; j < 8; j++) {
      int k = kf * 32 + kg * 8 + j;
      float w = W[(size_t)k * NFEAT + c] + (k == c ? 1.0f : 0.0f);
      unsigned short h = f2bf(w);
      hb[j] = (short)h;
      lb[j] = (short)f2bf(w - bf2f(h));
    }
    int base = ((m * 16 + kf * 4 + kg) << 10) + (c << 3);
    *(short8*)&Whi[base] = *(short8*)hb;
    *(short8*)&Wlo[base] = *(short8*)lb;
    return;
  }

  int t = (blockIdx.x - 24) * 256 + tid;   // 0..1535
  int cl = t / 512;
  int idx = t - cl * 512;
  int part = idx >> 7, k = idx & 127;
  float val;
  if (part == 0) {            // S: Wo1 + WtoI_top @ (Wo2-Wo1)
    float s = Wout[k * 3 + cl];
    for (int f = 0; f < 128; f++)
      s = fmaf(WtoI[k * 128 + f],
               Wout[(128 + f) * 3 + cl] - Wout[f * 3 + cl], s);
    val = s;
  } else if (part == 1) {     // I: Wo2 + WtoR @ (Wo3-Wo2)
    float s = Wout[(128 + k) * 3 + cl];
    for (int f = 0; f < 128; f++)
      s = fmaf(WtoR[k * 128 + f],
               Wout[(256 + f) * 3 + cl] - Wout[(128 + f) * 3 + cl], s);
    val = s;
  } else if (part == 2) {     // R: Wo3
    val = Wout[(256 + k) * 3 + cl];
  } else {                    // NB: WtoI_bot @ (Wo2-Wo1)
    float s = 0.f;
    for (int f = 0; f < 128; f++)
      s = fmaf(WtoI[(128 + k) * 128 + f],
               Wout[(128 + f) * 3 + cl] - Wout[f * 3 + cl], s);
    val = s;
  }
  MT[cl * 512 + idx] = val;

  if (blockIdx.x == 24 && tid < 3) {
    float s = bout[tid];
    for (int f = 0; f < 128; f++) {
      s = fmaf(btoI[f], Wout[(128 + f) * 3 + tid] - Wout[f * 3 + tid], s);
      s = fmaf(btoR[f], Wout[(256 + f) * 3 + tid] - Wout[(128 + f) * 3 + tid], s);
    }
    cb[tid] = s;
  }
}

// ---------------------------------------------------------------------------
// K1a (stats-only GEMM): column sum/sumsq of P_w = feat @ (W_w+I) + b_w.
// ---------------------------------------------------------------------------
__global__ __launch_bounds__(512, 2) void k1a_stats(
    const float* __restrict__ feat,
    const short* __restrict__ Whi, const short* __restrict__ Wlo,
    const float* __restrict__ bs, const float* __restrict__ bi,
    const float* __restrict__ br,
    float* __restrict__ stats,   // 6*128
    int N, int ntiles)
{
  __shared__ short Ah[2][64 * LDA];
  __shared__ short Al[2][64 * LDA];

  const int tid  = threadIdx.x;
  const int lane = tid & 63;
  const int wv   = tid >> 6;
  const int colb = wv * 16 + (lane & 15);
  const int kg   = lane >> 4;
  const int krow = kg * 8;

  const int sr = tid >> 3;
  const int so = tid & 7;

  const float bias[3] = {bs[colb], bi[colb], br[colb]};
  float ssum[3] = {0.f, 0.f, 0.f}, ssq[3] = {0.f, 0.f, 0.f};

  float4 pf[4];
  {
    int gr = blockIdx.x * 64 + sr; if (gr >= N) gr = N - 1;
    const float4* s4 = (const float4*)(feat + (size_t)gr * NFEAT + so * 16);
#pragma unroll
    for (int q = 0; q < 4; q++) pf[q] = s4[q];
    short hbuf[16], lbuf[16];
#pragma unroll
    for (int q = 0; q < 4; q++) {
      float xs[4] = {pf[q].x, pf[q].y, pf[q].z, pf[q].w};
#pragma unroll
      for (int cc = 0; cc < 4; cc++) {
        unsigned short h = f2bf(xs[cc]);
        hbuf[q * 4 + cc] = (short)h;
        lbuf[q * 4 + cc] = (short)f2bf(xs[cc] - bf2f(h));
      }
    }
    *(short8*)&Ah[0][sr * LDA + so * 16]     = *(short8*)(hbuf);
    *(short8*)&Ah[0][sr * LDA + so * 16 + 8] = *(short8*)(hbuf + 8);
    *(short8*)&Al[0][sr * LDA + so * 16]     = *(short8*)(lbuf);
    *(short8*)&Al[0][sr * LDA + so * 16 + 8] = *(short8*)(lbuf + 8);
  }
  __syncthreads();

  int cur = 0;
  for (int tile = blockIdx.x; tile < ntiles; tile += gridDim.x) {
    const int row0 = tile * 64;
    const int ntile = tile + gridDim.x;
    const bool have_next = ntile < ntiles;

    if (have_next) {
      int gr = ntile * 64 + sr; if (gr >= N) gr = N - 1;
      const float4* s4 = (const float4*)(feat + (size_t)gr * NFEAT + so * 16);
#pragma unroll
      for (int q = 0; q < 4; q++) pf[q] = s4[q];
    }

    const short* ah_c = &Ah[cur][0];
    const short* al_c = &Al[cur][0];

    f32x4 acc[3][4];
#pragma unroll
    for (int m = 0; m < 3; m++)
#pragma unroll
      for (int rf = 0; rf < 4; rf++)
        acc[m][rf] = (f32x4){0.f, 0.f, 0.f, 0.f};

#pragma unroll
    for (int kf = 0; kf < 4; kf++) {
      short8 bh[3], bl[3];
#pragma unroll
      for (int m = 0; m < 3; m++) {
        int fb = ((m * 16 + kf * 4 + kg) << 10) + (colb << 3);
        bh[m] = *(const short8*)&Whi[fb];
        bl[m] = *(const short8*)&Wlo[fb];
      }
      short8 ah[4], al[4];
#pragma unroll
      for (int rf = 0; rf < 4; rf++) {
        int off = (rf * 16 + (lane & 15)) * LDA + kf * 32 + krow;
        ah[rf] = *(const short8*)&ah_c[off];
        al[rf] = *(const short8*)&al_c[off];
      }
#pragma unroll
      for (int m = 0; m < 3; m++) {
#pragma unroll
        for (int rf = 0; rf < 4; rf++) {
          acc[m][rf] = __builtin_amdgcn_mfma_f32_16x16x32_bf16(
              ah[rf], bh[m], acc[m][rf], 0, 0, 0);
          acc[m][rf] = __builtin_amdgcn_mfma_f32_16x16x32_bf16(
              al[rf], bh[m], acc[m][rf], 0, 0, 0);
          acc[m][rf] = __builtin_amdgcn_mfma_f32_16x16x32_bf16(
              ah[rf], bl[m], acc[m][rf], 0, 0, 0);
        }
      }
    }

    // stats only (residual already in W' via +I)
#pragma unroll
    for (int rf = 0; rf < 4; rf++) {
      int lrb = rf * 16 + kg * 4;
#pragma unroll
      for (int g = 0; g < 4; g++) {
        bool ok = (row0 + lrb + g) < N;
#pragma unroll
        for (int m = 0; m < 3; m++) {
          float v = acc[m][rf][g] + bias[m];
          if (ok) { ssum[m] += v; ssq[m] += v * v; }
        }
      }
    }

    if (have_next) {
      short hbuf[16], lbuf[16];
#pragma unroll
      for (int q = 0; q < 4; q++) {
        float xs[4] = {pf[q].x, pf[q].y, pf[q].z, pf[q].w};
#pragma unroll
        for (int cc = 0; cc < 4; cc++) {
          unsigned short h = f2bf(xs[cc]);
          hbuf[q * 4 + cc] = (short)h;
          lbuf[q * 4 + cc] = (short)f2bf(xs[cc] - bf2f(h));
        }
      }
      int nb = cur ^ 1;
      *(short8*)&Ah[nb][sr * LDA + so * 16]     = *(short8*)(hbuf);
      *(short8*)&Ah[nb][sr * LDA + so * 16 + 8] = *(short8*)(hbuf + 8);
      *(short8*)&Al[nb][sr * LDA + so * 16]     = *(short8*)(lbuf);
      *(short8*)&Al[nb][sr * LDA + so * 16 + 8] = *(short8*)(lbuf + 8);
    }
    __syncthreads();
    cur ^= 1;
  }

#pragma unroll
  for (int m = 0; m < 3; m++) {
    float s = ssum[m], q = ssq[m];
    s += __shfl_xor(s, 16); s += __shfl_xor(s, 32);
    q += __shfl_xor(q, 16); q += __shfl_xor(q, 32);
    if (kg == 0) {
      unsafeAtomicAdd(&stats[m * 256 + colb], s);
      unsafeAtomicAdd(&stats[m * 256 + 128 + colb], q);
    }
  }
}

// ---------------------------------------------------------------------------
// K_bnscale: blocks 0..23: W'' = (W+I)·diag(a_m) split-bf16 (fragment order).
// Block 24: kvec[m][c] = a·(bias_m[c] − μ) + β.  a = γ·rsqrt(var+ε).
// ---------------------------------------------------------------------------
__global__ __launch_bounds__(256) void k_bnscale(
    const float* __restrict__ Ws, const float* __restrict__ Wi,
    const float* __restrict__ Wr,
    const float* __restrict__ bs, const float* __restrict__ bi,
    const float* __restrict__ br,
    const float* __restrict__ gamma, const float* __restrict__ beta,
    const float* __restrict__ stats,
    short* __restrict__ Whi2, short* __restrict__ Wlo2,
    float* __restrict__ kvec, float invN)
{
  const int tid = threadIdx.x;
  if (blockIdx.x < 24) {
    int t = blockIdx.x * 256 + tid;
    int m   = t >> 11;
    int rem = t & 2047;
    int kf  = rem >> 9;
    int kg  = (rem >> 7) & 3;
    int c   = rem & 127;
    const float* W = (m == 0) ? Ws : ((m == 1) ? Wi : Wr);
    float mu = stats[m * 256 + c] * invN;
    float var = stats[m * 256 + 128 + c] * invN - mu * mu;
    float a = gamma[c] * rsqrtf(var + EPSBN);
    short hb[8], lb[8];
#pragma unroll
    for (int j = 0; j < 8; j++) {
      int k = kf * 32 + kg * 8 + j;
      float w = (W[(size_t)k * NFEAT + c] + (k == c ? 1.0f : 0.0f)) * a;
      unsigned short h = f2bf(w);
      hb[j] = (short)h;
      lb[j] = (short)f2bf(w - bf2f(h));
    }
    int base = ((m * 16 + kf * 4 + kg) << 10) + (c << 3);
    *(short8*)&Whi2[base] = *(short8*)hb;
    *(short8*)&Wlo2[base] = *(short8*)lb;
    return;
  }
  // kvec
  if (tid < 384) {
    int m = tid >> 7, c = tid & 127;
    const float* B = (m == 0) ? bs : ((m == 1) ? bi : br);
    float mu = stats[m * 256 + c] * invN;
    float var = stats[m * 256 + 128 + c] * invN - mu * mu;
    float a = gamma[c] * rsqrtf(var + EPSBN);
    kvec[m * 128 + c] = a * (B[c] - mu) + beta[c];
  }
}

// ---------------------------------------------------------------------------
// K1f: fused main pass, register-lean version.  Wave owns 16 rows x 128 cols
// (8 waves -> 128 rows/block).  cg-outer: only ONE f32x4 accumulator live.
// acc = feat @ W''_m; v = relu(acc + kvec);
// slog[r][cl] += v·MT[cl][m*128+c];  q[r][cl] += v_i·MT[cl][384+c].
// Also zeroes logit3R for this block's rows.
// ---------------------------------------------------------------------------
__global__ __launch_bounds__(512, 2) void k1f_fused(
    const float* __restrict__ feat,
    const short* __restrict__ Whi2, const short* __restrict__ Wlo2,
    const float* __restrict__ MT, const float* __restrict__ kvec,
    float* __restrict__ slogA, float* __restrict__ qv,
    float* __restrict__ logit3R, int N, int N4)
{
  const int tid  = threadIdx.x;
  const int lane = tid & 63;
  const int wv   = tid >> 6;
  const int kg   = lane >> 4;
  const int l15  = lane & 15;

  // zero logit3R for this block's 128 rows x NREP reps (1024 float4, 2/thread)
  {
    int base_r = blockIdx.x * 128;
#pragma unroll
    for (int i = 0; i < 2; i++) {
      int idx = i * 512 + tid;
      int rep = idx >> 7;
      int ro  = idx & 127;
      int r = base_r + ro;
      if (r < N)
        *(float4*)&logit3R[(size_t)rep * N4 + (size_t)r * 4] =
            make_float4(0.f, 0.f, 0.f, 0.f);
    }
  }

  const int rowbase = blockIdx.x * 128 + wv * 16;

  // ---- A fragments (16 rows, split-bf16) in registers: 8 short8 = 32 VGPR
  short8 ah[4], al[4];
  {
    int r = rowbase + l15; if (r >= N) r = N - 1;
    const float4* fp = (const float4*)(feat + (size_t)r * NFEAT);
#pragma unroll
    for (int kf = 0; kf < 4; kf++) {
      float4 x0 = fp[kf * 8 + kg * 2];
      float4 x1 = fp[kf * 8 + kg * 2 + 1];
      float xs[8] = {x0.x, x0.y, x0.z, x0.w, x1.x, x1.y, x1.z, x1.w};
      short hb[8], lb[8];
#pragma unroll
      for (int j = 0; j < 8; j++) {
        unsigned short h = f2bf(xs[j]);
        hb[j] = (short)h;
        lb[j] = (short)f2bf(xs[j] - bf2f(h));
      }
      ah[kf] = *(short8*)hb;
      al[kf] = *(short8*)lb;
    }
  }

  float sac[4][3];   // slog partials per (g, cl)
  float qac[4][3];   // q partials
#pragma unroll
  for (int g = 0; g < 4; g++)
#pragma unroll
    for (int cl = 0; cl < 3; cl++) { sac[g][cl] = 0.f; qac[g][cl] = 0.f; }

#pragma unroll
  for (int m = 0; m < 3; m++) {
#pragma unroll
    for (int cg = 0; cg < 8; cg++) {
      f32x4 acc = (f32x4){0.f, 0.f, 0.f, 0.f};
#pragma unroll
      for (int kf = 0; kf < 4; kf++) {
        int fb = ((m * 16 + kf * 4 + kg) << 10) + ((cg * 16 + l15) << 3);
        short8 bh = *(const short8*)&Whi2[fb];
        short8 bl = *(const short8*)&Wlo2[fb];
        acc = __builtin_amdgcn_mfma_f32_16x16x32_bf16(ah[kf], bh, acc, 0, 0, 0);
        acc = __builtin_amdgcn_mfma_f32_16x16x32_bf16(al[kf], bh, acc, 0, 0, 0);
        acc = __builtin_amdgcn_mfma_f32_16x16x32_bf16(ah[kf], bl, acc, 0, 0, 0);
      }
      int c = cg * 16 + l15;
      float kc  = kvec[m * 128 + c];
      float mt0 = MT[0 * 512 + m * 128 + c];
      float mt1 = MT[1 * 512 + m * 128 + c];
      float mt2 = MT[2 * 512 + m * 128 + c];
      if (m == 1) {
        float mq0 = MT[0 * 512 + 384 + c];
        float mq1 = MT[1 * 512 + 384 + c];
        float mq2 = MT[2 * 512 + 384 + c];
#pragma unroll
        for (int g = 0; g < 4; g++) {
          float v = fmaxf(acc[g] + kc, 0.f);
          sac[g][0] = fmaf(v, mt0, sac[g][0]);
          sac[g][1] = fmaf(v, mt1, sac[g][1]);
          sac[g][2] = fmaf(v, mt2, sac[g][2]);
          qac[g][0] = fmaf(v, mq0, qac[g][0]);
          qac[g][1] = fmaf(v, mq1, qac[g][1]);
          qac[g][2] = fmaf(v, mq2, qac[g][2]);
        }
      } else {
#pragma unroll
        for (int g = 0; g < 4; g++) {
          float v = fmaxf(acc[g] + kc, 0.f);
          sac[g][0] = fmaf(v, mt0, sac[g][0]);
          sac[g][1] = fmaf(v, mt1, sac[g][1]);
          sac[g][2] = fmaf(v, mt2, sac[g][2]);
        }
      }
    }
  }

  // ---- reduce over 16 lanes (cols) and write slog / q
#pragma unroll
  for (int g = 0; g < 4; g++) {
    float s0 = sac[g][0], s1 = sac[g][1], s2 = sac[g][2];
    float q0 = qac[g][0], q1 = qac[g][1], q2 = qac[g][2];
#pragma unroll
    for (int off = 1; off < 16; off <<= 1) {
      s0 += __shfl_xor(s0, off); s1 += __shfl_xor(s1, off);
      s2 += __shfl_xor(s2, off);
      q0 += __shfl_xor(q0, off); q1 += __shfl_xor(q1, off);
      q2 += __shfl_xor(q2, off);
    }
    if (l15 == 0) {
      int r = rowbase + kg * 4 + g;
      if (r < N) {
        *(float4*)&slogA[(size_t)r * 4] = make_float4(s0, s1, s2, 0.f);
        *(float4*)&qv[(size_t)r * 4]    = make_float4(q0, q1, q2, 0.f);
      }
    }
  }
}

// ---------------------------------------------------------------------------
// K_edge: 64 lanes = 21 edges x 3 comps; one atomic/lane, same-line merge,
// replica (waveID&7) spreads contention.
// ---------------------------------------------------------------------------
__global__ __launch_bounds__(256) void k_edge(
    const int* __restrict__ eidx, const float* __restrict__ ew,
    const float* __restrict__ q, float* __restrict__ logit3R,
    int E, int N4)
{
  const int wid  = (blockIdx.x * 256 + threadIdx.x) >> 6;
  const int lane = threadIdx.x & 63;
  const int el   = lane / 3;
  const int comp = lane - el * 3;
  if (el >= 21) return;
  const int e = wid * 21 + el;
  if (e >= E) return;

  int src = eidx[e];
  int dst = eidx[E + e];
  float w = ew[e];
  float qvv = q[(size_t)src * 4 + comp];
  int rep = wid & (NREP - 1);
  unsafeAtomicAdd(&logit3R[(size_t)rep * N4 + (size_t)dst * 4 + comp], qvv * w);
}

// ---------------------------------------------------------------------------
// K4t: out[r] = softmax(slog[r] + sum_rep logit3R[rep][r] + cb).
// ---------------------------------------------------------------------------
__global__ __launch_bounds__(256) void k4_final(
    const float* __restrict__ slogA, const float* __restrict__ logit3R,
    const float* __restrict__ cb,
    float* __restrict__ out, int N, int N4)
{
  int r = blockIdx.x * 256 + threadIdx.x;
  if (r >= N) return;
  float4 S = *(const float4*)&slogA[(size_t)r * 4];
  float l0 = S.x + cb[0], l1 = S.y + cb[1], l2 = S.z + cb[2];
#pragma unroll
  for (int rep = 0; rep < NREP; rep++) {
    float4 L = *(const float4*)&logit3R[(size_t)rep * N4 + (size_t)r * 4];
    l0 += L.x; l1 += L.y; l2 += L.z;
  }
  float mx = fmaxf(l0, fmaxf(l1, l2));
  float e0 = expf(l0 - mx), e1 = expf(l1 - mx), e2 = expf(l2 - mx);
  float inv = 1.f / (e0 + e1 + e2);
  out[(size_t)r * 3 + 0] = e0 * inv;
  out[(size_t)r * 3 + 1] = e1 * inv;
  out[(size_t)r * 3 + 2] = e2 * inv;
}

// ---------------------------------------------------------------------------
extern "C" void kernel_launch(void* const* d_in, const int* in_sizes, int n_in,
                              void* d_out, int out_size, void* d_ws, size_t ws_size,
                              hipStream_t stream)
{
  const float* feat  = (const float*)d_in[0];
  const int*   eidx  = (const int*)  d_in[1];
  const float* ew    = (const float*)d_in[2];
  const float* Ws    = (const float*)d_in[3];
  const float* bs    = (const float*)d_in[4];
  const float* Wi    = (const float*)d_in[5];
  const float* bi    = (const float*)d_in[6];
  const float* Wr    = (const float*)d_in[7];
  const float* br    = (const float*)d_in[8];
  const float* gamma = (const float*)d_in[9];
  const float* beta  = (const float*)d_in[10];
  const float* WtoI  = (const float*)d_in[11];
  const float* btoI  = (const float*)d_in[12];
  const float* WtoR  = (const float*)d_in[13];
  const float* btoR  = (const float*)d_in[14];
  const float* Wout  = (const float*)d_in[15];
  const float* bout  = (const float*)d_in[16];

  const int N = in_sizes[0] / NFEAT;
  const int E = in_sizes[2];
  const int N4 = 4 * N;
  const float invN = 1.0f / (float)N;
  float* out = (float*)d_out;

  float* logit3R = (float*)d_ws;                 // NREP*4*N
  float* slogA   = logit3R + (size_t)NREP * N4;  // 4*N
  float* qv      = slogA + 4 * (size_t)N;        // 4*N
  float* stats   = qv + 4 * (size_t)N;           // 768
  float* MT      = stats + 768;                  // 1536
  float* cb      = MT + 1536;                    // 4
  float* kvec    = cb + 4;                       // 384
  short* Whi     = (short*)(kvec + 384);         // 49152
  short* Wlo     = Whi + 49152;                  // 49152
  short* Whi2    = Wlo + 49152;                  // 49152
  short* Wlo2    = Whi2 + 49152;                 // 49152

  hipMemsetAsync(stats, 0, 768 * sizeof(float), stream);

  const int nt = (N + 63) / 64;           // 1563
  const int g1 = (nt + 2) / 3;            // 521

  kp_params<<<30, 256, 0, stream>>>(Ws, Wi, Wr, WtoI, btoI, WtoR, btoR,
                                    Wout, bout, Whi, Wlo, MT, cb);
  k1a_stats<<<g1, 512, 0, stream>>>(feat, Whi, Wlo, bs, bi, br, stats, N, nt);
  k_bnscale<<<25, 256, 0, stream>>>(Ws, Wi, Wr, bs, bi, br, gamma, beta,
                                    stats, Whi2, Wlo2, kvec, invN);
  const int gf = (N + 127) / 128;         // 782
  k1f_fused<<<gf, 512, 0, stream>>>(feat, Whi2, Wlo2, MT, kvec,
                                    slogA, qv, logit3R, N, N4);
  const int nwaves = (E + 20) / 21;
  k_edge<<<(nwaves + 3) / 4, 256, 0, stream>>>(eidx, ew, qv, logit3R, E, N4);
  k4_final<<<(N + 255) / 256, 256, 0, stream>>>(slogA, logit3R, cb, out, N, N4);
}

// Round 12
// 169.735 us; speedup vs baseline: 1.5750x; 1.2919x over previous
//
#include <hip/hip_runtime.h>
#include <math.h>

#define NFEAT 128
#define EPSBN 1e-5f
#define LDA 136   // bf16 elems per LDS row: 128 + 8 pad
#define NREP 8    // logit3 replicas to spread atomic contention

typedef __attribute__((ext_vector_type(8))) short short8;
typedef __attribute__((ext_vector_type(4))) float f32x4;

__device__ __forceinline__ unsigned short f2bf(float x) {
  union { float f; unsigned u; } v; v.f = x;
  unsigned r = v.u + 0x7FFF + ((v.u >> 16) & 1);   // RNE
  return (unsigned short)(r >> 16);
}
__device__ __forceinline__ float bf2f(unsigned short h) {
  union { unsigned u; float f; } v; v.u = (unsigned)h << 16;
  return v.f;
}

// ---------------------------------------------------------------------------
// KP: blocks 0..23: split W' = (W + I) into bf16 hi/lo planes in MFMA
// B-fragment order (for the stats pass).  Blocks 24..29: fold back-half into
// MT + cb.  logits = S@M1 + I@M3 + R@M4 + NB@M2 + cb.
// MT layout: MT[cl*512 + part*128 + k], part: 0=S 1=I 2=R 3=NB.
// ---------------------------------------------------------------------------
__global__ __launch_bounds__(256) void kp_params(
    const float* __restrict__ Ws, const float* __restrict__ Wi,
    const float* __restrict__ Wr,
    const float* __restrict__ WtoI, const float* __restrict__ btoI,
    const float* __restrict__ WtoR, const float* __restrict__ btoR,
    const float* __restrict__ Wout, const float* __restrict__ bout,
    short* __restrict__ Whi, short* __restrict__ Wlo,
    float* __restrict__ MT, float* __restrict__ cb)
{
  const int tid = threadIdx.x;
  if (blockIdx.x < 24) {
    int t = blockIdx.x * 256 + tid;   // 6144 total
    int m   = t >> 11;
    int rem = t & 2047;
    int kf  = rem >> 9;
    int kg  = (rem >> 7) & 3;
    int c   = rem & 127;
    const float* W = (m == 0) ? Ws : ((m == 1) ? Wi : Wr);
    short hb[8], lb[8];
#pragma unroll
    for (int j = 0; j < 8; j++) {
      int k = kf * 32 + kg * 8 + j;
      float w = W[(size_t)k * NFEAT + c] + (k == c ? 1.0f : 0.0f);
      unsigned short h = f2bf(w);
      hb[j] = (short)h;
      lb[j] = (short)f2bf(w - bf2f(h));
    }
    int base = ((m * 16 + kf * 4 + kg) << 10) + (c << 3);
    *(short8*)&Whi[base] = *(short8*)hb;
    *(short8*)&Wlo[base] = *(short8*)lb;
    return;
  }

  int t = (blockIdx.x - 24) * 256 + tid;   // 0..1535
  int cl = t / 512;
  int idx = t - cl * 512;
  int part = idx >> 7, k = idx & 127;
  float val;
  if (part == 0) {            // S: Wo1 + WtoI_top @ (Wo2-Wo1)
    float s = Wout[k * 3 + cl];
    for (int f = 0; f < 128; f++)
      s = fmaf(WtoI[k * 128 + f],
               Wout[(128 + f) * 3 + cl] - Wout[f * 3 + cl], s);
    val = s;
  } else if (part == 1) {     // I: Wo2 + WtoR @ (Wo3-Wo2)
    float s = Wout[(128 + k) * 3 + cl];
    for (int f = 0; f < 128; f++)
      s = fmaf(WtoR[k * 128 + f],
               Wout[(256 + f) * 3 + cl] - Wout[(128 + f) * 3 + cl], s);
    val = s;
  } else if (part == 2) {     // R: Wo3
    val = Wout[(256 + k) * 3 + cl];
  } else {                    // NB: WtoI_bot @ (Wo2-Wo1)
    float s = 0.f;
    for (int f = 0; f < 128; f++)
      s = fmaf(WtoI[(128 + k) * 128 + f],
               Wout[(128 + f) * 3 + cl] - Wout[f * 3 + cl], s);
    val = s;
  }
  MT[cl * 512 + idx] = val;

  if (blockIdx.x == 24 && tid < 3) {
    float s = bout[tid];
    for (int f = 0; f < 128; f++) {
      s = fmaf(btoI[f], Wout[(128 + f) * 3 + tid] - Wout[f * 3 + tid], s);
      s = fmaf(btoR[f], Wout[(256 + f) * 3 + tid] - Wout[(128 + f) * 3 + tid], s);
    }
    cb[tid] = s;
  }
}

// ---------------------------------------------------------------------------
// K1a (stats-only GEMM): column sum/sumsq of P_w = feat @ (W_w+I) + b_w.
// ---------------------------------------------------------------------------
__global__ __launch_bounds__(512, 2) void k1a_stats(
    const float* __restrict__ feat,
    const short* __restrict__ Whi, const short* __restrict__ Wlo,
    const float* __restrict__ bs, const float* __restrict__ bi,
    const float* __restrict__ br,
    float* __restrict__ stats,   // 6*128
    int N, int ntiles)
{
  __shared__ short Ah[2][64 * LDA];
  __shared__ short Al[2][64 * LDA];

  const int tid  = threadIdx.x;
  const int lane = tid & 63;
  const int wv   = tid >> 6;
  const int colb = wv * 16 + (lane & 15);
  const int kg   = lane >> 4;
  const int krow = kg * 8;

  const int sr = tid >> 3;
  const int so = tid & 7;

  const float bias[3] = {bs[colb], bi[colb], br[colb]};
  float ssum[3] = {0.f, 0.f, 0.f}, ssq[3] = {0.f, 0.f, 0.f};

  float4 pf[4];
  {
    int gr = blockIdx.x * 64 + sr; if (gr >= N) gr = N - 1;
    const float4* s4 = (const float4*)(feat + (size_t)gr * NFEAT + so * 16);
#pragma unroll
    for (int q = 0; q < 4; q++) pf[q] = s4[q];
    short hbuf[16], lbuf[16];
#pragma unroll
    for (int q = 0; q < 4; q++) {
      float xs[4] = {pf[q].x, pf[q].y, pf[q].z, pf[q].w};
#pragma unroll
      for (int cc = 0; cc < 4; cc++) {
        unsigned short h = f2bf(xs[cc]);
        hbuf[q * 4 + cc] = (short)h;
        lbuf[q * 4 + cc] = (short)f2bf(xs[cc] - bf2f(h));
      }
    }
    *(short8*)&Ah[0][sr * LDA + so * 16]     = *(short8*)(hbuf);
    *(short8*)&Ah[0][sr * LDA + so * 16 + 8] = *(short8*)(hbuf + 8);
    *(short8*)&Al[0][sr * LDA + so * 16]     = *(short8*)(lbuf);
    *(short8*)&Al[0][sr * LDA + so * 16 + 8] = *(short8*)(lbuf + 8);
  }
  __syncthreads();

  int cur = 0;
  for (int tile = blockIdx.x; tile < ntiles; tile += gridDim.x) {
    const int row0 = tile * 64;
    const int ntile = tile + gridDim.x;
    const bool have_next = ntile < ntiles;

    if (have_next) {
      int gr = ntile * 64 + sr; if (gr >= N) gr = N - 1;
      const float4* s4 = (const float4*)(feat + (size_t)gr * NFEAT + so * 16);
#pragma unroll
      for (int q = 0; q < 4; q++) pf[q] = s4[q];
    }

    const short* ah_c = &Ah[cur][0];
    const short* al_c = &Al[cur][0];

    f32x4 acc[3][4];
#pragma unroll
    for (int m = 0; m < 3; m++)
#pragma unroll
      for (int rf = 0; rf < 4; rf++)
        acc[m][rf] = (f32x4){0.f, 0.f, 0.f, 0.f};

#pragma unroll
    for (int kf = 0; kf < 4; kf++) {
      short8 bh[3], bl[3];
#pragma unroll
      for (int m = 0; m < 3; m++) {
        int fb = ((m * 16 + kf * 4 + kg) << 10) + (colb << 3);
        bh[m] = *(const short8*)&Whi[fb];
        bl[m] = *(const short8*)&Wlo[fb];
      }
      short8 ah[4], al[4];
#pragma unroll
      for (int rf = 0; rf < 4; rf++) {
        int off = (rf * 16 + (lane & 15)) * LDA + kf * 32 + krow;
        ah[rf] = *(const short8*)&ah_c[off];
        al[rf] = *(const short8*)&al_c[off];
      }
#pragma unroll
      for (int m = 0; m < 3; m++) {
#pragma unroll
        for (int rf = 0; rf < 4; rf++) {
          acc[m][rf] = __builtin_amdgcn_mfma_f32_16x16x32_bf16(
              ah[rf], bh[m], acc[m][rf], 0, 0, 0);
          acc[m][rf] = __builtin_amdgcn_mfma_f32_16x16x32_bf16(
              al[rf], bh[m], acc[m][rf], 0, 0, 0);
          acc[m][rf] = __builtin_amdgcn_mfma_f32_16x16x32_bf16(
              ah[rf], bl[m], acc[m][rf], 0, 0, 0);
        }
      }
    }

    // stats only (residual already in W' via +I)
#pragma unroll
    for (int rf = 0; rf < 4; rf++) {
      int lrb = rf * 16 + kg * 4;
#pragma unroll
      for (int g = 0; g < 4; g++) {
        bool ok = (row0 + lrb + g) < N;
#pragma unroll
        for (int m = 0; m < 3; m++) {
          float v = acc[m][rf][g] + bias[m];
          if (ok) { ssum[m] += v; ssq[m] += v * v; }
        }
      }
    }

    if (have_next) {
      short hbuf[16], lbuf[16];
#pragma unroll
      for (int q = 0; q < 4; q++) {
        float xs[4] = {pf[q].x, pf[q].y, pf[q].z, pf[q].w};
#pragma unroll
        for (int cc = 0; cc < 4; cc++) {
          unsigned short h = f2bf(xs[cc]);
          hbuf[q * 4 + cc] = (short)h;
          lbuf[q * 4 + cc] = (short)f2bf(xs[cc] - bf2f(h));
        }
      }
      int nb = cur ^ 1;
      *(short8*)&Ah[nb][sr * LDA + so * 16]     = *(short8*)(hbuf);
      *(short8*)&Ah[nb][sr * LDA + so * 16 + 8] = *(short8*)(hbuf + 8);
      *(short8*)&Al[nb][sr * LDA + so * 16]     = *(short8*)(lbuf);
      *(short8*)&Al[nb][sr * LDA + so * 16 + 8] = *(short8*)(lbuf + 8);
    }
    __syncthreads();
    cur ^= 1;
  }

#pragma unroll
  for (int m = 0; m < 3; m++) {
    float s = ssum[m], q = ssq[m];
    s += __shfl_xor(s, 16); s += __shfl_xor(s, 32);
    q += __shfl_xor(q, 16); q += __shfl_xor(q, 32);
    if (kg == 0) {
      unsafeAtomicAdd(&stats[m * 256 + colb], s);
      unsafeAtomicAdd(&stats[m * 256 + 128 + colb], q);
    }
  }
}

// ---------------------------------------------------------------------------
// K_bnscale: blocks 0..23: W'' = (W+I)·diag(a_m) split-bf16 (fragment order).
// Block 24: kvec[m][c] = a·(bias_m[c] − μ) + β.  a = γ·rsqrt(var+ε).
// ---------------------------------------------------------------------------
__global__ __launch_bounds__(256) void k_bnscale(
    const float* __restrict__ Ws, const float* __restrict__ Wi,
    const float* __restrict__ Wr,
    const float* __restrict__ bs, const float* __restrict__ bi,
    const float* __restrict__ br,
    const float* __restrict__ gamma, const float* __restrict__ beta,
    const float* __restrict__ stats,
    short* __restrict__ Whi2, short* __restrict__ Wlo2,
    float* __restrict__ kvec, float invN)
{
  const int tid = threadIdx.x;
  if (blockIdx.x < 24) {
    int t = blockIdx.x * 256 + tid;
    int m   = t >> 11;
    int rem = t & 2047;
    int kf  = rem >> 9;
    int kg  = (rem >> 7) & 3;
    int c   = rem & 127;
    const float* W = (m == 0) ? Ws : ((m == 1) ? Wi : Wr);
    float mu = stats[m * 256 + c] * invN;
    float var = stats[m * 256 + 128 + c] * invN - mu * mu;
    float a = gamma[c] * rsqrtf(var + EPSBN);
    short hb[8], lb[8];
#pragma unroll
    for (int j = 0; j < 8; j++) {
      int k = kf * 32 + kg * 8 + j;
      float w = (W[(size_t)k * NFEAT + c] + (k == c ? 1.0f : 0.0f)) * a;
      unsigned short h = f2bf(w);
      hb[j] = (short)h;
      lb[j] = (short)f2bf(w - bf2f(h));
    }
    int base = ((m * 16 + kf * 4 + kg) << 10) + (c << 3);
    *(short8*)&Whi2[base] = *(short8*)hb;
    *(short8*)&Wlo2[base] = *(short8*)lb;
    return;
  }
  // kvec
  if (tid < 384) {
    int m = tid >> 7, c = tid & 127;
    const float* B = (m == 0) ? bs : ((m == 1) ? bi : br);
    float mu = stats[m * 256 + c] * invN;
    float var = stats[m * 256 + 128 + c] * invN - mu * mu;
    float a = gamma[c] * rsqrtf(var + EPSBN);
    kvec[m * 128 + c] = a * (B[c] - mu) + beta[c];
  }
}

// ---------------------------------------------------------------------------
// K1f v3: fused main pass.  Wave owns 16 rows x 128 cols; 8 waves/block.
// Per m: stage W''_m hi/lo into LDS (64 KB, shared by all waves), then
// process cg in PAIRS with 3 independent MFMA chains per cg (6 chains in
// flight) — breaks the R11 serial-chain latency; B from LDS kills the L2
// load-latency gate.  v = relu(acc + kvec); fold into slog/q partials.
// ---------------------------------------------------------------------------
__global__ __launch_bounds__(512, 2) void k1f_fused(
    const float* __restrict__ feat,
    const short* __restrict__ Whi2, const short* __restrict__ Wlo2,
    const float* __restrict__ MT, const float* __restrict__ kvec,
    float* __restrict__ slogA, float* __restrict__ qv,
    float* __restrict__ logit3R, int N, int N4)
{
  __shared__ short Bh[16384];   // 32 KB: W''_m hi, fragment order
  __shared__ short Bl[16384];   // 32 KB: W''_m lo

  const int tid  = threadIdx.x;
  const int lane = tid & 63;
  const int wv   = tid >> 6;
  const int kg   = lane >> 4;
  const int l15  = lane & 15;

  // zero logit3R for this block's 128 rows x NREP reps
  {
    int base_r = blockIdx.x * 128;
#pragma unroll
    for (int i = 0; i < 2; i++) {
      int idx = i * 512 + tid;
      int rep = idx >> 7;
      int ro  = idx & 127;
      int r = base_r + ro;
      if (r < N)
        *(float4*)&logit3R[(size_t)rep * N4 + (size_t)r * 4] =
            make_float4(0.f, 0.f, 0.f, 0.f);
    }
  }

  const int rowbase = blockIdx.x * 128 + wv * 16;

  // ---- A fragments (16 rows, split-bf16) in registers: 8 short8 = 32 VGPR
  short8 ah[4], al[4];
  {
    int r = rowbase + l15; if (r >= N) r = N - 1;
    const float4* fp = (const float4*)(feat + (size_t)r * NFEAT);
#pragma unroll
    for (int kf = 0; kf < 4; kf++) {
      float4 x0 = fp[kf * 8 + kg * 2];
      float4 x1 = fp[kf * 8 + kg * 2 + 1];
      float xs[8] = {x0.x, x0.y, x0.z, x0.w, x1.x, x1.y, x1.z, x1.w};
      short hb[8], lb[8];
#pragma unroll
      for (int j = 0; j < 8; j++) {
        unsigned short h = f2bf(xs[j]);
        hb[j] = (short)h;
        lb[j] = (short)f2bf(xs[j] - bf2f(h));
      }
      ah[kf] = *(short8*)hb;
      al[kf] = *(short8*)lb;
    }
  }

  float sac[4][3];   // slog partials per (g, cl)
  float qac[4][3];   // q partials
#pragma unroll
  for (int g = 0; g < 4; g++)
#pragma unroll
    for (int cl = 0; cl < 3; cl++) { sac[g][cl] = 0.f; qac[g][cl] = 0.f; }

  for (int m = 0; m < 3; m++) {
    // ---- stage W''_m hi/lo into LDS (4 short8 each per thread)
    __syncthreads();   // previous m's readers done
    {
      const short8* gh = (const short8*)(Whi2 + (m << 14));
      const short8* gl = (const short8*)(Wlo2 + (m << 14));
      short8* lh = (short8*)Bh;
      short8* ll = (short8*)Bl;
#pragma unroll
      for (int q = 0; q < 4; q++) {
        int slot = q * 512 + tid;    // 2048 short8 slots
        lh[slot] = gh[slot];
        ll[slot] = gl[slot];
      }
    }
    __syncthreads();

#pragma unroll
    for (int cgp = 0; cgp < 4; cgp++) {
      const int cg0 = cgp * 2, cg1 = cgp * 2 + 1;
      // 3 independent chains per cg, 2 cgs => 6 chains in flight
      f32x4 aA0 = {0.f,0.f,0.f,0.f}, aB0 = {0.f,0.f,0.f,0.f}, aC0 = {0.f,0.f,0.f,0.f};
      f32x4 aA1 = {0.f,0.f,0.f,0.f}, aB1 = {0.f,0.f,0.f,0.f}, aC1 = {0.f,0.f,0.f,0.f};
#pragma unroll
      for (int kf = 0; kf < 4; kf++) {
        int base0 = ((kf * 4 + kg) << 10) + ((cg0 * 16 + l15) << 3);
        int base1 = ((kf * 4 + kg) << 10) + ((cg1 * 16 + l15) << 3);
        short8 bh0 = *(const short8*)&Bh[base0];
        short8 bl0 = *(const short8*)&Bl[base0];
        short8 bh1 = *(const short8*)&Bh[base1];
        short8 bl1 = *(const short8*)&Bl[base1];
        aA0 = __builtin_amdgcn_mfma_f32_16x16x32_bf16(ah[kf], bh0, aA0, 0, 0, 0);
        aA1 = __builtin_amdgcn_mfma_f32_16x16x32_bf16(ah[kf], bh1, aA1, 0, 0, 0);
        aB0 = __builtin_amdgcn_mfma_f32_16x16x32_bf16(al[kf], bh0, aB0, 0, 0, 0);
        aB1 = __builtin_amdgcn_mfma_f32_16x16x32_bf16(al[kf], bh1, aB1, 0, 0, 0);
        aC0 = __builtin_amdgcn_mfma_f32_16x16x32_bf16(ah[kf], bl0, aC0, 0, 0, 0);
        aC1 = __builtin_amdgcn_mfma_f32_16x16x32_bf16(ah[kf], bl1, aC1, 0, 0, 0);
      }
      // epilogue for cg0 and cg1
#pragma unroll
      for (int s = 0; s < 2; s++) {
        int c = (s == 0 ? cg0 : cg1) * 16 + l15;
        f32x4 aA = s == 0 ? aA0 : aA1;
        f32x4 aB = s == 0 ? aB0 : aB1;
        f32x4 aC = s == 0 ? aC0 : aC1;
        float kc  = kvec[m * 128 + c];
        float mt0 = MT[0 * 512 + m * 128 + c];
        float mt1 = MT[1 * 512 + m * 128 + c];
        float mt2 = MT[2 * 512 + m * 128 + c];
        if (m == 1) {
          float mq0 = MT[0 * 512 + 384 + c];
          float mq1 = MT[1 * 512 + 384 + c];
          float mq2 = MT[2 * 512 + 384 + c];
#pragma unroll
          for (int g = 0; g < 4; g++) {
            float v = fmaxf(aA[g] + aB[g] + aC[g] + kc, 0.f);
            sac[g][0] = fmaf(v, mt0, sac[g][0]);
            sac[g][1] = fmaf(v, mt1, sac[g][1]);
            sac[g][2] = fmaf(v, mt2, sac[g][2]);
            qac[g][0] = fmaf(v, mq0, qac[g][0]);
            qac[g][1] = fmaf(v, mq1, qac[g][1]);
            qac[g][2] = fmaf(v, mq2, qac[g][2]);
          }
        } else {
#pragma unroll
          for (int g = 0; g < 4; g++) {
            float v = fmaxf(aA[g] + aB[g] + aC[g] + kc, 0.f);
            sac[g][0] = fmaf(v, mt0, sac[g][0]);
            sac[g][1] = fmaf(v, mt1, sac[g][1]);
            sac[g][2] = fmaf(v, mt2, sac[g][2]);
          }
        }
      }
    }
  }

  // ---- reduce over 16 lanes (cols) and write slog / q
#pragma unroll
  for (int g = 0; g < 4; g++) {
    float s0 = sac[g][0], s1 = sac[g][1], s2 = sac[g][2];
    float q0 = qac[g][0], q1 = qac[g][1], q2 = qac[g][2];
#pragma unroll
    for (int off = 1; off < 16; off <<= 1) {
      s0 += __shfl_xor(s0, off); s1 += __shfl_xor(s1, off);
      s2 += __shfl_xor(s2, off);
      q0 += __shfl_xor(q0, off); q1 += __shfl_xor(q1, off);
      q2 += __shfl_xor(q2, off);
    }
    if (l15 == 0) {
      int r = rowbase + kg * 4 + g;
      if (r < N) {
        *(float4*)&slogA[(size_t)r * 4] = make_float4(s0, s1, s2, 0.f);
        *(float4*)&qv[(size_t)r * 4]    = make_float4(q0, q1, q2, 0.f);
      }
    }
  }
}

// ---------------------------------------------------------------------------
// K_edge: 64 lanes = 21 edges x 3 comps; one atomic/lane, same-line merge,
// replica (waveID&7) spreads contention.
// ---------------------------------------------------------------------------
__global__ __launch_bounds__(256) void k_edge(
    const int* __restrict__ eidx, const float* __restrict__ ew,
    const float* __restrict__ q, float* __restrict__ logit3R,
    int E, int N4)
{
  const int wid  = (blockIdx.x * 256 + threadIdx.x) >> 6;
  const int lane = threadIdx.x & 63;
  const int el   = lane / 3;
  const int comp = lane - el * 3;
  if (el >= 21) return;
  const int e = wid * 21 + el;
  if (e >= E) return;

  int src = eidx[e];
  int dst = eidx[E + e];
  float w = ew[e];
  float qvv = q[(size_t)src * 4 + comp];
  int rep = wid & (NREP - 1);
  unsafeAtomicAdd(&logit3R[(size_t)rep * N4 + (size_t)dst * 4 + comp], qvv * w);
}

// ---------------------------------------------------------------------------
// K4t: out[r] = softmax(slog[r] + sum_rep logit3R[rep][r] + cb).
// ---------------------------------------------------------------------------
__global__ __launch_bounds__(256) void k4_final(
    const float* __restrict__ slogA, const float* __restrict__ logit3R,
    const float* __restrict__ cb,
    float* __restrict__ out, int N, int N4)
{
  int r = blockIdx.x * 256 + threadIdx.x;
  if (r >= N) return;
  float4 S = *(const float4*)&slogA[(size_t)r * 4];
  float l0 = S.x + cb[0], l1 = S.y + cb[1], l2 = S.z + cb[2];
#pragma unroll
  for (int rep = 0; rep < NREP; rep++) {
    float4 L = *(const float4*)&logit3R[(size_t)rep * N4 + (size_t)r * 4];
    l0 += L.x; l1 += L.y; l2 += L.z;
  }
  float mx = fmaxf(l0, fmaxf(l1, l2));
  float e0 = expf(l0 - mx), e1 = expf(l1 - mx), e2 = expf(l2 - mx);
  float inv = 1.f / (e0 + e1 + e2);
  out[(size_t)r * 3 + 0] = e0 * inv;
  out[(size_t)r * 3 + 1] = e1 * inv;
  out[(size_t)r * 3 + 2] = e2 * inv;
}

// ---------------------------------------------------------------------------
extern "C" void kernel_launch(void* const* d_in, const int* in_sizes, int n_in,
                              void* d_out, int out_size, void* d_ws, size_t ws_size,
                              hipStream_t stream)
{
  const float* feat  = (const float*)d_in[0];
  const int*   eidx  = (const int*)  d_in[1];
  const float* ew    = (const float*)d_in[2];
  const float* Ws    = (const float*)d_in[3];
  const float* bs    = (const float*)d_in[4];
  const float* Wi    = (const float*)d_in[5];
  const float* bi    = (const float*)d_in[6];
  const float* Wr    = (const float*)d_in[7];
  const float* br    = (const float*)d_in[8];
  const float* gamma = (const float*)d_in[9];
  const float* beta  = (const float*)d_in[10];
  const float* WtoI  = (const float*)d_in[11];
  const float* btoI  = (const float*)d_in[12];
  const float* WtoR  = (const float*)d_in[13];
  const float* btoR  = (const float*)d_in[14];
  const float* Wout  = (const float*)d_in[15];
  const float* bout  = (const float*)d_in[16];

  const int N = in_sizes[0] / NFEAT;
  const int E = in_sizes[2];
  const int N4 = 4 * N;
  const float invN = 1.0f / (float)N;
  float* out = (float*)d_out;

  float* logit3R = (float*)d_ws;                 // NREP*4*N
  float* slogA   = logit3R + (size_t)NREP * N4;  // 4*N
  float* qv      = slogA + 4 * (size_t)N;        // 4*N
  float* stats   = qv + 4 * (size_t)N;           // 768
  float* MT      = stats + 768;                  // 1536
  float* cb      = MT + 1536;                    // 4
  float* kvec    = cb + 4;                       // 384
  short* Whi     = (short*)(kvec + 384);         // 49152
  short* Wlo     = Whi + 49152;                  // 49152
  short* Whi2    = Wlo + 49152;                  // 49152
  short* Wlo2    = Whi2 + 49152;                 // 49152

  hipMemsetAsync(stats, 0, 768 * sizeof(float), stream);

  const int nt = (N + 63) / 64;           // 1563
  const int g1 = (nt + 2) / 3;            // 521

  kp_params<<<30, 256, 0, stream>>>(Ws, Wi, Wr, WtoI, btoI, WtoR, btoR,
                                    Wout, bout, Whi, Wlo, MT, cb);
  k1a_stats<<<g1, 512, 0, stream>>>(feat, Whi, Wlo, bs, bi, br, stats, N, nt);
  k_bnscale<<<25, 256, 0, stream>>>(Ws, Wi, Wr, bs, bi, br, gamma, beta,
                                    stats, Whi2, Wlo2, kvec, invN);
  const int gf = (N + 127) / 128;         // 782
  k1f_fused<<<gf, 512, 0, stream>>>(feat, Whi2, Wlo2, MT, kvec,
                                    slogA, qv, logit3R, N, N4);
  const int nwaves = (E + 20) / 21;
  k_edge<<<(nwaves + 3) / 4, 256, 0, stream>>>(eidx, ew, qv, logit3R, E, N4);
  k4_final<<<(N + 255) / 256, 256, 0, stream>>>(slogA, logit3R, cb, out, N, N4);
}